// Round 3
// baseline (755.715 us; speedup 1.0000x reference)
//
#include <hip/hip_runtime.h>
#include <hip/hip_bf16.h>
#include <math.h>

#define H 256
#define EDIM 6
#define NEG 0.2f
#define LN_EPS 1e-5f
#define NPAD 20096   // 157 * 128

typedef __bf16 bf16x8 __attribute__((ext_vector_type(8)));
typedef float  floatx4 __attribute__((ext_vector_type(4)));

__device__ __forceinline__ float b2f(unsigned short u) {
    union { unsigned int i; float f; } v; v.i = ((unsigned int)u) << 16; return v.f;
}
__device__ __forceinline__ unsigned short f2bu(float f) {
    __hip_bfloat16 h = __float2bfloat16(f);
    return *(unsigned short*)&h;
}

// ---------------------------------------------------------------------------
// CSR build
// ---------------------------------------------------------------------------
__global__ void k_edge_hist(const int* __restrict__ ei, int* __restrict__ deg, int E) {
    int e = blockIdx.x * blockDim.x + threadIdx.x;
    if (e >= E) return;
    atomicAdd(&deg[ei[E + e]], 1);
}

__global__ void k_scan(const int* __restrict__ deg, int* __restrict__ row_ptr,
                       int* __restrict__ cursor, int N, int E) {
    __shared__ int wsum[16];
    __shared__ int wpre[16];
    __shared__ int s_carry;
    int tid = threadIdx.x;
    int lane = tid & 63, wv = tid >> 6;
    if (tid == 0) s_carry = 0;
    __syncthreads();
    for (int base = 0; base < N; base += 1024) {
        int i = base + tid;
        int v = (i < N) ? deg[i] : 0;
        int x = v;
#pragma unroll
        for (int d = 1; d < 64; d <<= 1) {
            int y = __shfl_up(x, d);
            if (lane >= d) x += y;
        }
        if (lane == 63) wsum[wv] = x;
        __syncthreads();
        int total = 0;
        if (tid == 0) {
            int a = 0;
            for (int w = 0; w < 16; w++) { wpre[w] = a; a += wsum[w]; }
            total = a;
        }
        __syncthreads();
        int excl = s_carry + wpre[wv] + (x - v);
        if (i < N) { row_ptr[i] = excl; cursor[i] = excl; }
        __syncthreads();
        if (tid == 0) s_carry += total;
        __syncthreads();
    }
    if (tid == 0) row_ptr[N] = E;
}

// ea padded to 8 floats/edge so k_gat can use aligned uniform float4 loads
__global__ void k_scatter(const int* __restrict__ ei, const float* __restrict__ eattr,
                          int* __restrict__ cursor, int* __restrict__ src_sorted,
                          float* __restrict__ ea_pad, int E) {
    int e = blockIdx.x * blockDim.x + threadIdx.x;
    if (e >= E) return;
    int s = ei[e], d = ei[E + e];
    int pos = atomicAdd(&cursor[d], 1);
    src_sorted[pos] = s;
    float4 lo, hi;
    lo.x = eattr[e * EDIM + 0]; lo.y = eattr[e * EDIM + 1];
    lo.z = eattr[e * EDIM + 2]; lo.w = eattr[e * EDIM + 3];
    hi.x = eattr[e * EDIM + 4]; hi.y = eattr[e * EDIM + 5];
    hi.z = 0.f; hi.w = 0.f;
    *(float4*)&ea_pad[(size_t)pos * 8]     = lo;
    *(float4*)&ea_pad[(size_t)pos * 8 + 4] = hi;
}

// ---------------------------------------------------------------------------
// Weight conversions to transposed bf16 [c][k]
// ---------------------------------------------------------------------------
__global__ void k_conv_x(const float* __restrict__ x, __hip_bfloat16* __restrict__ xb, int N) {
    int idx = blockIdx.x * blockDim.x + threadIdx.x;
    if (idx >= NPAD * 32) return;
    int r = idx >> 5, k = idx & 31;
    float v = (r < N && k < 23) ? x[r * 23 + k] : 0.f;
    xb[idx] = __float2bfloat16(v);
}

__global__ void k_conv_w0(const float* __restrict__ Wl0, const float* __restrict__ Wr0,
                          __hip_bfloat16* __restrict__ out) {
    int idx = blockIdx.x * blockDim.x + threadIdx.x;
    if (idx >= 2 * 256 * 32) return;
    int mat = idx >> 13, rem = idx & 8191;
    int c = rem >> 5, k = rem & 31;
    const float* W = mat ? Wr0 : Wl0;
    float v = (k < 23) ? W[k * 256 + c] : 0.f;
    out[idx] = __float2bfloat16(v);
}

__global__ void k_conv_w(const float* __restrict__ Wl, const float* __restrict__ Wr,
                         const float* __restrict__ lin, __hip_bfloat16* __restrict__ out) {
    int idx = blockIdx.x * blockDim.x + threadIdx.x;
    if (idx >= 7 * 65536) return;
    int mat = idx >> 16, rem = idx & 65535;
    int c = rem >> 8, k = rem & 255;
    const float* W = (mat < 3) ? (Wl + (size_t)mat * 65536)
                   : (mat < 6) ? (Wr + (size_t)(mat - 3) * 65536)
                   : lin;
    out[idx] = __float2bfloat16(W[k * 256 + c]);
}

// ---------------------------------------------------------------------------
// MFMA dual GEMM, K as compile-time constant. mat0 can emit bf16 and/or f32.
// ---------------------------------------------------------------------------
template<int K>
__global__ __launch_bounds__(256) void k_gemm_mfma(
    const __hip_bfloat16* __restrict__ A, int N,
    const __hip_bfloat16* __restrict__ Wt1, const float* __restrict__ b1,
    float* __restrict__ C1f, unsigned short* __restrict__ C1b,
    const __hip_bfloat16* __restrict__ Wt2, const float* __restrict__ b2,
    float* __restrict__ C2) {
    int tid = threadIdx.x;
    int wv = tid >> 6, lane = tid & 63;
    int quad = lane >> 4, l16 = lane & 15;
    int mat = blockIdx.x >> 1;
    int c0 = (blockIdx.x & 1) * 128;
    int r0 = blockIdx.y * 128;
    const __hip_bfloat16* Wt = mat ? Wt2 : Wt1;
    const float* bv = mat ? b2 : b1;
    int wm = wv >> 1, wn = wv & 1;
    int rbase = r0 + wm * 64;
    int cbase = c0 + wn * 64;

    floatx4 acc[4][4] = {};
    const __bf16* Ab = (const __bf16*)A;
    const __bf16* Bb = (const __bf16*)Wt;
#pragma unroll 2
    for (int k0 = 0; k0 < K; k0 += 32) {
        bf16x8 a[4], b[4];
        const __bf16* Ap = Ab + (size_t)(rbase + l16) * K + k0 + quad * 8;
#pragma unroll
        for (int mi = 0; mi < 4; mi++)
            a[mi] = *(const bf16x8*)(Ap + (size_t)mi * 16 * K);
        const __bf16* Bp = Bb + (size_t)(cbase + l16) * K + k0 + quad * 8;
#pragma unroll
        for (int ni = 0; ni < 4; ni++)
            b[ni] = *(const bf16x8*)(Bp + (size_t)ni * 16 * K);
#pragma unroll
        for (int mi = 0; mi < 4; mi++)
#pragma unroll
            for (int ni = 0; ni < 4; ni++)
                acc[mi][ni] = __builtin_amdgcn_mfma_f32_16x16x32_bf16(a[mi], b[ni], acc[mi][ni], 0, 0, 0);
    }
#pragma unroll
    for (int ni = 0; ni < 4; ni++) {
        int c = cbase + ni * 16 + l16;
        float bb = bv[c];
#pragma unroll
        for (int mi = 0; mi < 4; mi++) {
#pragma unroll
            for (int r = 0; r < 4; r++) {
                int gr = rbase + mi * 16 + quad * 4 + r;
                if (gr >= N) continue;
                float val = acc[mi][ni][r] + bb;
                if (mat == 0) {
                    if (C1b) C1b[(size_t)gr * H + c] = f2bu(val);
                    if (C1f) C1f[(size_t)gr * H + c] = val;
                } else {
                    C2[(size_t)gr * H + c] = val;
                }
            }
        }
    }
}

// ---------------------------------------------------------------------------
// Fused GATv2 edge pass: one wave per node, bf16 gathers, uniform edge-attr
// loads (no broadcast shuffles), 2-edge unroll, online softmax, fused
// bias+LayerNorm+ReLU, bf16 output.
// ---------------------------------------------------------------------------
__global__ __launch_bounds__(256) void k_gat(
    const unsigned short* __restrict__ hlb, const float* __restrict__ hr,
    const int* __restrict__ row_ptr, const int* __restrict__ src_sorted,
    const float* __restrict__ ea_pad,
    const float* __restrict__ We, const float* __restrict__ attv,
    const float* __restrict__ bias, const float* __restrict__ lnw,
    const float* __restrict__ lnb, unsigned short* __restrict__ hout, int N) {
    int wv = threadIdx.x >> 6;
    int lane = threadIdx.x & 63;
    int node = blockIdx.x * 4 + wv;
    if (node >= N) return;
    int cb = lane * 4;

    float we[EDIM][4];
#pragma unroll
    for (int k = 0; k < EDIM; k++) {
        float4 t = *(const float4*)&We[k * H + cb];
        we[k][0] = t.x; we[k][1] = t.y; we[k][2] = t.z; we[k][3] = t.w;
    }
    float4 t;
    t = *(const float4*)&attv[cb];
    float av[4] = {t.x, t.y, t.z, t.w};
    t = *(const float4*)&hr[(size_t)node * H + cb];
    float hrd[4] = {t.x, t.y, t.z, t.w};
    ushort4 hu = *(const ushort4*)&hlb[(size_t)node * H + cb];
    float hli[4] = {b2f(hu.x), b2f(hu.y), b2f(hu.z), b2f(hu.w)};

    float mmax = -INFINITY;
    float denom = 0.f;
    float acc[4] = {0.f, 0.f, 0.f, 0.f};
    float es[EDIM] = {0.f, 0.f, 0.f, 0.f, 0.f, 0.f};

    int e0 = row_ptr[node], e1 = row_ptr[node + 1];
    int e = e0;
    for (; e + 2 <= e1; e += 2) {
        int s0 = src_sorted[e];
        int s1 = src_sorted[e + 1];
        float4 a0 = *(const float4*)&ea_pad[(size_t)e * 8];
        float4 c0 = *(const float4*)&ea_pad[(size_t)e * 8 + 4];
        float4 a1 = *(const float4*)&ea_pad[(size_t)(e + 1) * 8];
        float4 c1 = *(const float4*)&ea_pad[(size_t)(e + 1) * 8 + 4];
        ushort4 u0 = *(const ushort4*)&hlb[(size_t)s0 * H + cb];
        ushort4 u1 = *(const ushort4*)&hlb[(size_t)s1 * H + cb];
        es[0] += a0.x + a1.x; es[1] += a0.y + a1.y; es[2] += a0.z + a1.z;
        es[3] += a0.w + a1.w; es[4] += c0.x + c1.x; es[5] += c0.y + c1.y;
        float hs0[4] = {b2f(u0.x), b2f(u0.y), b2f(u0.z), b2f(u0.w)};
        float hs1[4] = {b2f(u1.x), b2f(u1.y), b2f(u1.z), b2f(u1.w)};
        float ea0[EDIM] = {a0.x, a0.y, a0.z, a0.w, c0.x, c0.y};
        float ea1[EDIM] = {a1.x, a1.y, a1.z, a1.w, c1.x, c1.y};
        float p0 = 0.f, p1 = 0.f;
#pragma unroll
        for (int j = 0; j < 4; j++) {
            float v0 = hs0[j] + hrd[j];
            float v1 = hs1[j] + hrd[j];
#pragma unroll
            for (int k = 0; k < EDIM; k++) {
                v0 = fmaf(ea0[k], we[k][j], v0);
                v1 = fmaf(ea1[k], we[k][j], v1);
            }
            v0 = (v0 > 0.f) ? v0 : NEG * v0;
            v1 = (v1 > 0.f) ? v1 : NEG * v1;
            p0 = fmaf(v0, av[j], p0);
            p1 = fmaf(v1, av[j], p1);
        }
#pragma unroll
        for (int d = 1; d < 64; d <<= 1) {
            p0 += __shfl_xor(p0, d);
            p1 += __shfl_xor(p1, d);
        }
        float nm = fmaxf(mmax, fmaxf(p0, p1));
        float scale = __expf(mmax - nm);
        float w0 = __expf(p0 - nm);
        float w1 = __expf(p1 - nm);
        denom = denom * scale + w0 + w1;
#pragma unroll
        for (int j = 0; j < 4; j++)
            acc[j] = fmaf(acc[j], scale, fmaf(w0, hs0[j], w1 * hs1[j]));
        mmax = nm;
    }
    if (e < e1) {
        int s0 = src_sorted[e];
        float4 a0 = *(const float4*)&ea_pad[(size_t)e * 8];
        float4 c0 = *(const float4*)&ea_pad[(size_t)e * 8 + 4];
        ushort4 u0 = *(const ushort4*)&hlb[(size_t)s0 * H + cb];
        es[0] += a0.x; es[1] += a0.y; es[2] += a0.z;
        es[3] += a0.w; es[4] += c0.x; es[5] += c0.y;
        float hs0[4] = {b2f(u0.x), b2f(u0.y), b2f(u0.z), b2f(u0.w)};
        float ea0[EDIM] = {a0.x, a0.y, a0.z, a0.w, c0.x, c0.y};
        float p0 = 0.f;
#pragma unroll
        for (int j = 0; j < 4; j++) {
            float v0 = hs0[j] + hrd[j];
#pragma unroll
            for (int k = 0; k < EDIM; k++) v0 = fmaf(ea0[k], we[k][j], v0);
            v0 = (v0 > 0.f) ? v0 : NEG * v0;
            p0 = fmaf(v0, av[j], p0);
        }
#pragma unroll
        for (int d = 1; d < 64; d <<= 1) p0 += __shfl_xor(p0, d);
        float nm = fmaxf(mmax, p0);
        float scale = __expf(mmax - nm);
        float w0 = __expf(p0 - nm);
        denom = denom * scale + w0;
#pragma unroll
        for (int j = 0; j < 4; j++) acc[j] = fmaf(acc[j], scale, w0 * hs0[j]);
        mmax = nm;
    }

    // self loop: edge_attr = mean of incoming attrs (all lanes have full es[])
    {
        float inv_deg = 1.f / fmaxf((float)(e1 - e0), 1.f);
        float p = 0.f;
#pragma unroll
        for (int j = 0; j < 4; j++) {
            float v = hli[j] + hrd[j];
#pragma unroll
            for (int k = 0; k < EDIM; k++) v = fmaf(es[k] * inv_deg, we[k][j], v);
            v = (v > 0.f) ? v : NEG * v;
            p = fmaf(v, av[j], p);
        }
#pragma unroll
        for (int d = 1; d < 64; d <<= 1) p += __shfl_xor(p, d);
        float nm = fmaxf(mmax, p);
        float scale = __expf(mmax - nm);
        float w = __expf(p - nm);
        denom = denom * scale + w;
#pragma unroll
        for (int j = 0; j < 4; j++) acc[j] = fmaf(acc[j], scale, w * hli[j]);
    }

    float inv = 1.f / denom;
    t = *(const float4*)&bias[cb];
    float o[4];
    o[0] = acc[0] * inv + t.x;
    o[1] = acc[1] * inv + t.y;
    o[2] = acc[2] * inv + t.z;
    o[3] = acc[3] * inv + t.w;

    float s = o[0] + o[1] + o[2] + o[3];
#pragma unroll
    for (int d = 1; d < 64; d <<= 1) s += __shfl_xor(s, d);
    float mu = s * (1.f / 256.f);
    float vs = 0.f;
#pragma unroll
    for (int j = 0; j < 4; j++) { float dd = o[j] - mu; vs += dd * dd; }
#pragma unroll
    for (int d = 1; d < 64; d <<= 1) vs += __shfl_xor(vs, d);
    float rstd = rsqrtf(vs * (1.f / 256.f) + LN_EPS);

    float4 w4 = *(const float4*)&lnw[cb];
    float4 b4 = *(const float4*)&lnb[cb];
    ushort4 outv;
    outv.x = f2bu(fmaxf((o[0] - mu) * rstd * w4.x + b4.x, 0.f));
    outv.y = f2bu(fmaxf((o[1] - mu) * rstd * w4.y + b4.y, 0.f));
    outv.z = f2bu(fmaxf((o[2] - mu) * rstd * w4.z + b4.z, 0.f));
    outv.w = f2bu(fmaxf((o[3] - mu) * rstd * w4.w + b4.w, 0.f));
    *(ushort4*)&hout[(size_t)node * H + cb] = outv;
}

// ---------------------------------------------------------------------------
// Global mean pool per graph (batch sorted): one block per graph.
// ---------------------------------------------------------------------------
__global__ __launch_bounds__(256) void k_pool(const float* __restrict__ hf,
                                              const int* __restrict__ batch,
                                              float* __restrict__ out, int N) {
    __shared__ int s_lo, s_hi;
    int g = blockIdx.x, c = threadIdx.x;
    if (c == 0) {
        int lo = 0, hi = N;
        while (lo < hi) { int mid = (lo + hi) >> 1; if (batch[mid] < g) lo = mid + 1; else hi = mid; }
        s_lo = lo;
    }
    if (c == 1) {
        int lo = 0, hi = N;
        while (lo < hi) { int mid = (lo + hi) >> 1; if (batch[mid] < g + 1) lo = mid + 1; else hi = mid; }
        s_hi = lo;
    }
    __syncthreads();
    int lo = s_lo, hi = s_hi;
    float s = 0.f;
    for (int n = lo; n < hi; n++) s += hf[(size_t)n * H + c];
    float cnt = fmaxf((float)(hi - lo), 1.f);
    out[g * H + c] = s / cnt;
}

// ---------------------------------------------------------------------------
extern "C" void kernel_launch(void* const* d_in, const int* in_sizes, int n_in,
                              void* d_out, int out_size, void* d_ws, size_t ws_size,
                              hipStream_t stream) {
    const float* x        = (const float*)d_in[0];
    const int*   ei       = (const int*)d_in[1];
    const float* eattr    = (const float*)d_in[2];
    const int*   batch    = (const int*)d_in[3];
    const float* W_l0     = (const float*)d_in[4];
    const float* W_r0     = (const float*)d_in[5];
    const float* W_l      = (const float*)d_in[6];
    const float* W_r      = (const float*)d_in[7];
    const float* b_l      = (const float*)d_in[8];
    const float* b_r      = (const float*)d_in[9];
    const float* W_e      = (const float*)d_in[10];
    const float* att      = (const float*)d_in[11];
    const float* bias     = (const float*)d_in[12];
    const float* ln_w     = (const float*)d_in[13];
    const float* ln_b     = (const float*)d_in[14];
    const float* lin_W    = (const float*)d_in[15];
    const float* lin_b    = (const float*)d_in[16];

    const int N = in_sizes[0] / 23;          // 20000
    const int E = in_sizes[1] / 2;           // 320000
    const int G = out_size / H;              // 64
    const int L = 4;

    // workspace layout
    char* p = (char*)d_ws;
    float* hr = (float*)p;                        p += (size_t)N * H * 4;     // hr; reused as final f32 h
    float* ea_pad = (float*)p;                    p += (size_t)E * 8 * 4;
    unsigned short* hlb = (unsigned short*)p;     p += (size_t)N * H * 2;
    unsigned short* hb  = (unsigned short*)p;     p += (size_t)NPAD * H * 2;
    __hip_bfloat16* xb  = (__hip_bfloat16*)p;     p += (size_t)NPAD * 32 * 2;
    __hip_bfloat16* w0t = (__hip_bfloat16*)p;     p += (size_t)2 * 256 * 32 * 2;
    __hip_bfloat16* wbig = (__hip_bfloat16*)p;    p += (size_t)7 * 65536 * 2;
    int* deg      = (int*)p;                      p += (size_t)N * 4;
    int* row_ptr  = (int*)p;                      p += (size_t)(N + 1) * 4;
    int* cursor   = (int*)p;                      p += (size_t)N * 4;
    int* src_sort = (int*)p;                      p += (size_t)E * 4;

    __hip_bfloat16* Wl0t = w0t;
    __hip_bfloat16* Wr0t = w0t + 8192;
    __hip_bfloat16* Wlt  = wbig;
    __hip_bfloat16* Wrt  = wbig + (size_t)3 * 65536;
    __hip_bfloat16* linWt = wbig + (size_t)6 * 65536;

    hipMemsetAsync(deg, 0, (size_t)N * sizeof(int), stream);
    hipMemsetAsync(hb + (size_t)N * H, 0, (size_t)(NPAD - N) * H * 2, stream);

    int tb = 256;
    k_conv_x<<<(NPAD * 32 + tb - 1) / tb, tb, 0, stream>>>(x, xb, N);
    k_conv_w0<<<(2 * 256 * 32 + tb - 1) / tb, tb, 0, stream>>>(W_l0, W_r0, w0t);
    k_conv_w<<<(7 * 65536 + tb - 1) / tb, tb, 0, stream>>>(W_l, W_r, lin_W, wbig);

    k_edge_hist<<<(E + tb - 1) / tb, tb, 0, stream>>>(ei, deg, E);
    k_scan<<<1, 1024, 0, stream>>>(deg, row_ptr, cursor, N, E);
    k_scatter<<<(E + tb - 1) / tb, tb, 0, stream>>>(ei, eattr, cursor, src_sort, ea_pad, E);

    dim3 gdual(4, NPAD / 128), gsingle(2, NPAD / 128), blk(256);

    for (int l = 0; l < L; l++) {
        const __hip_bfloat16* A  = (l == 0) ? xb : (const __hip_bfloat16*)hb;
        const __hip_bfloat16* Wl = (l == 0) ? Wl0t : (Wlt + (size_t)(l - 1) * 65536);
        const __hip_bfloat16* Wr = (l == 0) ? Wr0t : (Wrt + (size_t)(l - 1) * 65536);
        if (l == 0)
            k_gemm_mfma<32><<<gdual, blk, 0, stream>>>(A, N, Wl, b_l + l * H, nullptr, hlb,
                                                       Wr, b_r + l * H, hr);
        else
            k_gemm_mfma<256><<<gdual, blk, 0, stream>>>(A, N, Wl, b_l + l * H, nullptr, hlb,
                                                        Wr, b_r + l * H, hr);
        k_gat<<<(N + 3) / 4, 256, 0, stream>>>(hlb, hr, row_ptr, src_sort, ea_pad,
                                               W_e + (size_t)l * EDIM * H, att + l * H,
                                               bias + l * H, ln_w + l * H, ln_b + l * H, hb, N);
    }

    // final projection (f32 out into hr buffer), then pool
    k_gemm_mfma<256><<<gsingle, blk, 0, stream>>>((const __hip_bfloat16*)hb, N, linWt, lin_b,
                                                  hr, nullptr, nullptr, nullptr, nullptr);
    k_pool<<<G, 256, 0, stream>>>(hr, batch, (float*)d_out, N);
}